// Round 8
// baseline (104.476 us; speedup 1.0000x reference)
//
#include <hip/hip_runtime.h>
#include <math.h>

#define D_MODEL 512
#define NHEADS  8
#define NSEQ    2048
#define NBLK    16
#define NCHUNK  72          // sum over m of (m/2+1)
#define EPSF    1e-6f
#define WPLANE  262144      // 512*512 elements per weight plane

typedef _Float16 v8h __attribute__((ext_vector_type(8)));
typedef _Float16 v4h __attribute__((ext_vector_type(4)));
typedef float    v4f __attribute__((ext_vector_type(4)));

static __device__ __forceinline__ v4f mfma16h(v8h a, v8h b, v4f c) {
  return __builtin_amdgcn_mfma_f32_16x16x32_f16(a, b, c, 0, 0, 0);
}

// ---------------------------------------------------------------------------
// W[k][n] fp32 -> Wt[n][k] fp16 (4 matrices)
__global__ __launch_bounds__(256) void prep_w(const float* __restrict__ W0,
                                              const float* __restrict__ W1,
                                              const float* __restrict__ W2,
                                              const float* __restrict__ W3,
                                              _Float16* __restrict__ Wth) {
  __shared__ float T[64][68];
  const int z = blockIdx.z;
  const float* W = (z == 0) ? W0 : (z == 1) ? W1 : (z == 2) ? W2 : W3;
  const int kb = blockIdx.x * 64;
  const int nb = blockIdx.y * 64;
  const int tid = threadIdx.x;
#pragma unroll
  for (int l = 0; l < 4; ++l) {
    int f = tid + l * 256;           // 64 rows(k) x 16 float4(n)
    int row = f >> 4, c4 = f & 15;
    float4 v = *reinterpret_cast<const float4*>(&W[(size_t)(kb + row) * D_MODEL + nb + c4 * 4]);
    T[c4 * 4 + 0][row] = v.x; T[c4 * 4 + 1][row] = v.y;
    T[c4 * 4 + 2][row] = v.z; T[c4 * 4 + 3][row] = v.w;
  }
  __syncthreads();
  _Float16* oh = Wth + (size_t)z * WPLANE;
#pragma unroll
  for (int l = 0; l < 4; ++l) {
    int f = tid + l * 256;           // 64 rows(n) x 16 groups of 4(k)
    int n_ = f >> 4, k4 = f & 15;
    v4h h4;
    h4[0] = (_Float16)T[n_][k4 * 4 + 0];
    h4[1] = (_Float16)T[n_][k4 * 4 + 1];
    h4[2] = (_Float16)T[n_][k4 * 4 + 2];
    h4[3] = (_Float16)T[n_][k4 * 4 + 3];
    *reinterpret_cast<v4h*>(&oh[(size_t)(nb + n_) * D_MODEL + kb + k4 * 4]) = h4;
  }
}

// ---------------------------------------------------------------------------
// Q/K/V projections, 1-term fp16 MFMA. Norms from ROUNDED fp16 outputs.
// V (z==2) is written directly TRANSPOSED into Vtb[col][row] (col-major).
__global__ __launch_bounds__(256) void qkv_gemm(
    const float* __restrict__ x, const _Float16* __restrict__ Wth,
    const float* __restrict__ bq, const float* __restrict__ bk,
    const float* __restrict__ bv,
    _Float16* __restrict__ Qp, _Float16* __restrict__ Kp,
    _Float16* __restrict__ Vtb,
    float* __restrict__ Qn_, float* __restrict__ Kn_) {
  __shared__ _Float16 Ah[128][40], Bh[128][40];
  const int z = blockIdx.z;
  const _Float16* Bt = Wth + (size_t)z * WPLANE;
  const float* bias = (z == 0) ? bq : (z == 1) ? bk : bv;
  _Float16* outp = (z == 0) ? Qp : Kp;

  const int bx = blockIdx.x, by = blockIdx.y;
  const int tid = threadIdx.x;
  const int wid = tid >> 6, lane = tid & 63;
  const int wr = wid >> 1, wc = wid & 1;
  const int g = lane >> 4, lx = lane & 15;

  v4f acc[4][4];
#pragma unroll
  for (int i = 0; i < 4; ++i)
#pragma unroll
    for (int j = 0; j < 4; ++j) acc[i][j] = v4f{0.f, 0.f, 0.f, 0.f};

  for (int k0 = 0; k0 < 16; ++k0) {
    __syncthreads();
#pragma unroll
    for (int l = 0; l < 4; ++l) {
      int f = tid + l * 256;          // 128 rows x 8 float4 (32 k)
      int row = f >> 3, c4 = f & 7;
      float4 a = *reinterpret_cast<const float4*>(&x[(size_t)(by * 128 + row) * D_MODEL + k0 * 32 + c4 * 4]);
      Ah[row][c4 * 4 + 0] = (_Float16)a.x;
      Ah[row][c4 * 4 + 1] = (_Float16)a.y;
      Ah[row][c4 * 4 + 2] = (_Float16)a.z;
      Ah[row][c4 * 4 + 3] = (_Float16)a.w;
    }
#pragma unroll
    for (int l = 0; l < 2; ++l) {
      int f = tid + l * 256;          // 128 rows x 4 chunks of 8
      int row = f >> 2, c8 = f & 3;
      *reinterpret_cast<uint4*>(&Bh[row][c8 * 8]) =
          *reinterpret_cast<const uint4*>(&Bt[(size_t)(bx * 128 + row) * D_MODEL + k0 * 32 + c8 * 8]);
    }
    __syncthreads();
    v8h ah[4], bh[4];
#pragma unroll
    for (int i = 0; i < 4; ++i) {
      ah[i] = *reinterpret_cast<const v8h*>(&Ah[wr * 64 + i * 16 + lx][g * 8]);
      bh[i] = *reinterpret_cast<const v8h*>(&Bh[wc * 64 + i * 16 + lx][g * 8]);
    }
#pragma unroll
    for (int i = 0; i < 4; ++i)
#pragma unroll
      for (int j = 0; j < 4; ++j)
        acc[i][j] = mfma16h(ah[i], bh[j], acc[i][j]);
  }

  float np[4][4];
#pragma unroll
  for (int i = 0; i < 4; ++i)
#pragma unroll
    for (int r = 0; r < 4; ++r) np[i][r] = 0.f;

#pragma unroll
  for (int j = 0; j < 4; ++j) {
    const int col = bx * 128 + wc * 64 + j * 16 + lx;
    const float bj = bias[col];
#pragma unroll
    for (int i = 0; i < 4; ++i)
#pragma unroll
      for (int r = 0; r < 4; ++r) {
        const int row = by * 128 + wr * 64 + i * 16 + g * 4 + r;
        float v = acc[i][j][r] + bj;
        _Float16 hv = (_Float16)v;
        if (z == 2) Vtb[(size_t)col * NSEQ + row] = hv;     // transposed V
        else        outp[(size_t)row * D_MODEL + col] = hv;
        float vr = (float)hv;                 // rounded value for the norm
        np[i][r] = fmaf(vr, vr, np[i][r]);
      }
  }
  if (z < 2) {
    float* Nout = (z == 0) ? Qn_ : Kn_;
    const int hh = bx * 2 + wc;               // head of this wave's 64 cols
#pragma unroll
    for (int i = 0; i < 4; ++i)
#pragma unroll
      for (int r = 0; r < 4; ++r) {
        float s = np[i][r];
        s += __shfl_xor(s, 1, 64);
        s += __shfl_xor(s, 2, 64);
        s += __shfl_xor(s, 4, 64);
        s += __shfl_xor(s, 8, 64);
        if (lx == 0)
          Nout[hh * NSEQ + by * 128 + wr * 64 + i * 16 + g * 4 + r] = s;
      }
  }
}

// ---------------------------------------------------------------------------
// Attention. grid 576, h = bid&7 (head->XCD affinity). 512 thr = 8 waves,
// 3 WG/CU (LDS 53.2 KB). K,V LDS-staged with register prefetch; E buffer
// halved (two exp->Es->PV passes after one full-row max). Es wave-private.
__global__ __launch_bounds__(512, 6) void attn(
    const _Float16* __restrict__ Qp, const _Float16* __restrict__ Kp,
    const _Float16* __restrict__ Vtb, const float* __restrict__ Qn,
    const float* __restrict__ Kn, const float* __restrict__ cptr,
    _Float16* __restrict__ Opart, float* __restrict__ Npart)
{
  __shared__ _Float16 Khs[128][68];
  __shared__ _Float16 Vs[64][140];
  __shared__ _Float16 Es[8][16][68];
  __shared__ float kns[128];

  const int bid = blockIdx.x;
  const int h    = bid & 7;
  const int pid2 = bid >> 3;          // chunk 0..71
  int m = 0, base = 0;
  while (base + (m / 2 + 1) <= pid2) { base += m / 2 + 1; ++m; }
  const int c  = pid2 - base;
  const int n0 = 2 * c;
  const int n1 = (n0 + 1 < m) ? n0 + 1 : m;

  const int tid  = threadIdx.x;
  const int w    = tid >> 6;
  const int lane = tid & 63;
  const int g = lane >> 4, lx = lane & 15;

  const float cc = fmaxf(fabsf(cptr[0]), 1e-6f);
  const float is = rsqrtf(cc);
  const bool is_one = (cc == 1.0f);
  const float two_cc = 2.f * cc;

  // staging indices
  const int krow = tid >> 3, kc8 = tid & 7;      // K: 128 rows x 8 chunks(8)
  const int vrow = tid >> 4, vc8 = tid & 15;     // V: 64 rows(d) x 16 chunks(8), 2x

  const _Float16* Kgh = Kp + h * 64;
  const _Float16* Vgh = Vtb + (size_t)(h * 64) * NSEQ;

  // ---- prologue: load n0 tiles, write LDS ----
  uint4 kpre0, kpre1, vpre0, vpre1;
  float knp = 0.f;
  {
    const _Float16* Kg = Kgh + (size_t)(n0 * 128) * D_MODEL;
    kpre0 = *reinterpret_cast<const uint4*>(&Kg[(size_t)krow * D_MODEL + kc8 * 8]);
    kpre1 = *reinterpret_cast<const uint4*>(&Kg[(size_t)(krow + 64) * D_MODEL + kc8 * 8]);
    vpre0 = *reinterpret_cast<const uint4*>(&Vgh[(size_t)vrow * NSEQ + n0 * 128 + vc8 * 8]);
    vpre1 = *reinterpret_cast<const uint4*>(&Vgh[(size_t)(vrow + 32) * NSEQ + n0 * 128 + vc8 * 8]);
    if (tid < 128) knp = Kn[h * NSEQ + n0 * 128 + tid];
  }
  *reinterpret_cast<uint4*>(&Khs[krow][kc8 * 8]) = kpre0;
  *reinterpret_cast<uint4*>(&Khs[krow + 64][kc8 * 8]) = kpre1;
  *reinterpret_cast<uint4*>(&Vs[vrow][vc8 * 8]) = vpre0;
  *reinterpret_cast<uint4*>(&Vs[vrow + 32][vc8 * 8]) = vpre1;
  if (tid < 128) kns[tid] = knp;
  __syncthreads();

  // Q fragments + norms from global
  v8h aQ[2];
  {
    const size_t qoff = (size_t)(m * 128 + 16 * w + lx) * D_MODEL + h * 64 + g * 8;
    aQ[0] = *reinterpret_cast<const v8h*>(&Qp[qoff]);
    aQ[1] = *reinterpret_cast<const v8h*>(&Qp[qoff + 32]);
  }
  float qnr[4], qar[4];
#pragma unroll
  for (int r = 0; r < 4; ++r) {
    qnr[r] = Qn[h * NSEQ + m * 128 + 16 * w + g * 4 + r];
    qar[r] = fmaf(-cc, qnr[r], 1.f);
  }

  v4f o_acc[4];
#pragma unroll
  for (int td = 0; td < 4; ++td) o_acc[td] = v4f{0.f, 0.f, 0.f, 0.f};
  float nrm[4] = {0.f, 0.f, 0.f, 0.f};

  for (int n = n0; n <= n1; ++n) {
    const bool more = (n < n1);
    if (more) {                       // issue n+1 loads; they fly over compute
      const _Float16* Kg = Kgh + (size_t)((n + 1) * 128) * D_MODEL;
      kpre0 = *reinterpret_cast<const uint4*>(&Kg[(size_t)krow * D_MODEL + kc8 * 8]);
      kpre1 = *reinterpret_cast<const uint4*>(&Kg[(size_t)(krow + 64) * D_MODEL + kc8 * 8]);
      vpre0 = *reinterpret_cast<const uint4*>(&Vgh[(size_t)vrow * NSEQ + (n + 1) * 128 + vc8 * 8]);
      vpre1 = *reinterpret_cast<const uint4*>(&Vgh[(size_t)(vrow + 32) * NSEQ + (n + 1) * 128 + vc8 * 8]);
      if (tid < 128) knp = Kn[h * NSEQ + (n + 1) * 128 + tid];
    }

    // ---- S = Q.K^T (1-term fp16) ----
    v4f acc[8];
    __builtin_amdgcn_s_setprio(1);
#pragma unroll
    for (int tn = 0; tn < 8; ++tn) {
      v8h b0 = *reinterpret_cast<const v8h*>(&Khs[tn * 16 + lx][g * 8]);
      v8h b1 = *reinterpret_cast<const v8h*>(&Khs[tn * 16 + lx][g * 8 + 32]);
      v4f a = v4f{0.f, 0.f, 0.f, 0.f};
      a = mfma16h(aQ[0], b0, a);
      a = mfma16h(aQ[1], b1, a);
      acc[tn] = a;
    }
    __builtin_amdgcn_s_setprio(0);

    // ---- u = arg + sqrt(arg^2-1), arg = 1 + t ----
    const bool diag = (n == m);
#pragma unroll
    for (int tn = 0; tn < 8; ++tn) {
      const int col = tn * 16 + lx;
      const float knc = kns[col];
      const float kac = fmaf(-cc, knc, 1.f);
#pragma unroll
      for (int r = 0; r < 4; ++r) {
        const int rowl = 16 * w + g * 4 + r;
        float dsq = fmaxf(fmaf(-2.f, acc[tn][r], qnr[r] + knc), 0.f);
        float den = fmaxf(qar[r] * kac, EPSF);
        float t = fmaxf(two_cc * dsq * __builtin_amdgcn_rcpf(den), EPSF);
        float u = 1.f + t + __builtin_amdgcn_sqrtf(t * (t + 2.f));
        if (diag && col > rowl) u = __builtin_inff();
        acc[tn][r] = u;
      }
    }

    // ---- full-row reduction (umin for c==1, smax otherwise) ----
    float mred[4];
    if (is_one) {
#pragma unroll
      for (int r = 0; r < 4; ++r) mred[r] = __builtin_inff();
#pragma unroll
      for (int tn = 0; tn < 8; ++tn)
#pragma unroll
        for (int r = 0; r < 4; ++r) mred[r] = fminf(mred[r], acc[tn][r]);
#pragma unroll
      for (int d = 1; d < 16; d <<= 1)
#pragma unroll
        for (int r = 0; r < 4; ++r) mred[r] = fminf(mred[r], __shfl_xor(mred[r], d, 64));
    } else {
#pragma unroll
      for (int r = 0; r < 4; ++r) mred[r] = -__builtin_inff();
#pragma unroll
      for (int tn = 0; tn < 8; ++tn)
#pragma unroll
        for (int r = 0; r < 4; ++r) {
          float s = -__logf(acc[tn][r]) * is;      // u=inf -> -inf
          acc[tn][r] = s;
          mred[r] = fmaxf(mred[r], s);
        }
#pragma unroll
      for (int d = 1; d < 16; d <<= 1)
#pragma unroll
        for (int r = 0; r < 4; ++r) mred[r] = fmaxf(mred[r], __shfl_xor(mred[r], d, 64));
    }

    // ---- two halves: exp -> Es(half) -> PV(half) ----
#pragma unroll
    for (int half = 0; half < 2; ++half) {
#pragma unroll
      for (int tn2 = 0; tn2 < 4; ++tn2) {
        const int tn = half * 4 + tn2;
#pragma unroll
        for (int r = 0; r < 4; ++r) {
          float e = is_one ? mred[r] * __builtin_amdgcn_rcpf(acc[tn][r])
                           : __expf(acc[tn][r] - mred[r]);
          nrm[r] += e;
          Es[w][g * 4 + r][tn2 * 16 + lx] = (_Float16)e;
        }
      }
      // Es is wave-private: drain this wave's ds_writes, no block barrier.
      asm volatile("s_waitcnt lgkmcnt(0)" ::: "memory");
      __builtin_amdgcn_sched_barrier(0);
      __builtin_amdgcn_s_setprio(1);
#pragma unroll
      for (int ks2 = 0; ks2 < 2; ++ks2) {
        const int ks = half * 2 + ks2;
        v8h ea = *reinterpret_cast<const v8h*>(&Es[w][lx][ks2 * 32 + g * 8]);
#pragma unroll
        for (int td = 0; td < 4; ++td) {
          v8h vb = *reinterpret_cast<const v8h*>(&Vs[td * 16 + lx][ks * 32 + g * 8]);
          o_acc[td] = mfma16h(ea, vb, o_acc[td]);
        }
      }
      __builtin_amdgcn_s_setprio(0);
    }

    if (more) {                       // swap in the prefetched tiles
      __syncthreads();                // everyone done reading Khs/Vs/kns
      *reinterpret_cast<uint4*>(&Khs[krow][kc8 * 8]) = kpre0;
      *reinterpret_cast<uint4*>(&Khs[krow + 64][kc8 * 8]) = kpre1;
      *reinterpret_cast<uint4*>(&Vs[vrow][vc8 * 8]) = vpre0;
      *reinterpret_cast<uint4*>(&Vs[vrow + 32][vc8 * 8]) = vpre1;
      if (tid < 128) kns[tid] = knp;
      __syncthreads();
    }
  }

  // ---- norm reduce across tx, write partials (fp16 Opart) ----
#pragma unroll
  for (int d = 1; d < 16; d <<= 1)
#pragma unroll
    for (int r = 0; r < 4; ++r) nrm[r] += __shfl_xor(nrm[r], d, 64);

  _Float16* Op = Opart + ((size_t)h * NCHUNK + pid2) * (128 * 64);
#pragma unroll
  for (int td = 0; td < 4; ++td)
#pragma unroll
    for (int r = 0; r < 4; ++r)
      Op[(size_t)(16 * w + g * 4 + r) * 64 + td * 16 + lx] = (_Float16)o_acc[td][r];
  if (lx == 0) {
#pragma unroll
    for (int r = 0; r < 4; ++r)
      Npart[((size_t)h * NCHUNK + pid2) * 128 + 16 * w + g * 4 + r] = nrm[r];
  }
}

// ---------------------------------------------------------------------------
// Sum partials over chunks, normalize -> Of (fp16). grid (64, 8), 32 rows/WG.
__global__ __launch_bounds__(256) void reduce_o(const _Float16* __restrict__ Opart,
                                                const float* __restrict__ Npart,
                                                _Float16* __restrict__ Of) {
  const int mq = blockIdx.x;
  const int mm = mq >> 2;
  const int rq = (mq & 3) * 32;
  const int h  = blockIdx.y;
  const int tid = threadIdx.x;
  int base = 0;
  for (int k = 0; k < mm; ++k) base += k / 2 + 1;
  const int nch = mm / 2 + 1;

  __shared__ float innorm[32];
  if (tid < 32) {
    float s = 0.f;
    for (int cI = 0; cI < nch; ++cI)
      s += Npart[((size_t)h * NCHUNK + base + cI) * 128 + rq + tid];
    innorm[tid] = 1.f / fmaxf(s, EPSF);
  }
  __syncthreads();
#pragma unroll
  for (int l = 0; l < 2; ++l) {
    int f = tid + l * 256;            // 32 rows x 16 groups of 4
    int r = f >> 4, c4 = f & 15;
    float s0 = 0.f, s1 = 0.f, s2 = 0.f, s3 = 0.f;
    for (int cI = 0; cI < nch; ++cI) {
      const v4h p = *reinterpret_cast<const v4h*>(
          &Opart[((size_t)h * NCHUNK + base + cI) * 8192 + (size_t)(rq + r) * 64 + c4 * 4]);
      s0 += (float)p[0]; s1 += (float)p[1]; s2 += (float)p[2]; s3 += (float)p[3];
    }
    float inv = innorm[r];
    v4h o4;
    o4[0] = (_Float16)(s0 * inv); o4[1] = (_Float16)(s1 * inv);
    o4[2] = (_Float16)(s2 * inv); o4[3] = (_Float16)(s3 * inv);
    *reinterpret_cast<v4h*>(
        &Of[(size_t)(mm * 128 + rq + r) * D_MODEL + h * 64 + c4 * 4]) = o4;
  }
}

// ---------------------------------------------------------------------------
// out = Of @ Wo + bo, 1-term fp16. 64x64 tiles, grid (8,32) = 256 WGs.
__global__ __launch_bounds__(256) void o_gemm(const _Float16* __restrict__ Of,
                                              const _Float16* __restrict__ Wth,
                                              const float* __restrict__ bo,
                                              float* __restrict__ out) {
  __shared__ _Float16 As[64][40], Bs[64][40];
  const _Float16* Bt = Wth + (size_t)3 * WPLANE;
  const int bx = blockIdx.x, by = blockIdx.y;
  const int tid = threadIdx.x;
  const int wid = tid >> 6, lane = tid & 63;
  const int wr = wid >> 1, wc = wid & 1;
  const int g = lane >> 4, lx = lane & 15;

  v4f acc[2][2];
#pragma unroll
  for (int i = 0; i < 2; ++i)
#pragma unroll
    for (int j = 0; j < 2; ++j) acc[i][j] = v4f{0.f, 0.f, 0.f, 0.f};

  const int srow = tid >> 2, sc8 = tid & 3;   // 64 rows x 4 chunks(8)
  for (int k0 = 0; k0 < 16; ++k0) {
    __syncthreads();
    *reinterpret_cast<uint4*>(&As[srow][sc8 * 8]) =
        *reinterpret_cast<const uint4*>(&Of[(size_t)(by * 64 + srow) * D_MODEL + k0 * 32 + sc8 * 8]);
    *reinterpret_cast<uint4*>(&Bs[srow][sc8 * 8]) =
        *reinterpret_cast<const uint4*>(&Bt[(size_t)(bx * 64 + srow) * D_MODEL + k0 * 32 + sc8 * 8]);
    __syncthreads();
    v8h ah[2], bh[2];
#pragma unroll
    for (int i = 0; i < 2; ++i) {
      ah[i] = *reinterpret_cast<const v8h*>(&As[wr * 32 + i * 16 + lx][g * 8]);
      bh[i] = *reinterpret_cast<const v8h*>(&Bs[wc * 32 + i * 16 + lx][g * 8]);
    }
#pragma unroll
    for (int i = 0; i < 2; ++i)
#pragma unroll
      for (int j = 0; j < 2; ++j)
        acc[i][j] = mfma16h(ah[i], bh[j], acc[i][j]);
  }
#pragma unroll
  for (int j = 0; j < 2; ++j) {
    const int col = bx * 64 + wc * 32 + j * 16 + lx;
    const float bj = bo[col];
#pragma unroll
    for (int i = 0; i < 2; ++i)
#pragma unroll
      for (int r = 0; r < 4; ++r) {
        const int row = by * 64 + wr * 32 + i * 16 + g * 4 + r;
        out[(size_t)row * D_MODEL + col] = acc[i][j][r] + bj;
      }
  }
}

// ---------------------------------------------------------------------------
extern "C" void kernel_launch(void* const* d_in, const int* in_sizes, int n_in,
                              void* d_out, int out_size, void* d_ws, size_t ws_size,
                              hipStream_t stream) {
  (void)in_sizes; (void)n_in; (void)out_size; (void)ws_size;
  const float* x  = (const float*)d_in[0];
  const float* cfg= (const float*)d_in[1];
  const float* Wq = (const float*)d_in[2];
  const float* bq = (const float*)d_in[3];
  const float* Wk = (const float*)d_in[4];
  const float* bk = (const float*)d_in[5];
  const float* Wv = (const float*)d_in[6];
  const float* bv = (const float*)d_in[7];
  const float* Wo = (const float*)d_in[8];
  const float* bo = (const float*)d_in[9];
  float* out = (float*)d_out;

  char* p = (char*)d_ws;
  const size_t PL = (size_t)NSEQ * D_MODEL * sizeof(_Float16);   // 2 MiB
  _Float16* Wth = (_Float16*)p;        p += 4 * (size_t)WPLANE * sizeof(_Float16);
  _Float16* Qp  = (_Float16*)p;        p += PL;
  _Float16* Kp  = (_Float16*)p;        p += PL;
  _Float16* Vtb = (_Float16*)p;        p += PL;
  _Float16* Of  = (_Float16*)p;        p += PL;
  float*  Qn  = (float*)p;             p += (size_t)NHEADS * NSEQ * sizeof(float);
  float*  Kn  = (float*)p;             p += (size_t)NHEADS * NSEQ * sizeof(float);
  _Float16* Opart = (_Float16*)p;      p += (size_t)NHEADS * NCHUNK * 8192 * sizeof(_Float16);
  float*  Npart = (float*)p;

  prep_w<<<dim3(8, 8, 4), 256, 0, stream>>>(Wq, Wk, Wv, Wo, Wth);
  qkv_gemm<<<dim3(4, 16, 3), 256, 0, stream>>>(x, Wth, bq, bk, bv,
                                               Qp, Kp, Vtb, Qn, Kn);
  attn<<<dim3(NCHUNK * NHEADS), 512, 0, stream>>>(Qp, Kp, Vtb, Qn, Kn, cfg,
                                                  Opart, Npart);
  reduce_o<<<dim3(64, NHEADS), 256, 0, stream>>>(Opart, Npart, Of);
  o_gemm<<<dim3(8, 32), 256, 0, stream>>>(Of, Wth, bo, out);
}